// Round 10
// baseline (70.650 us; speedup 1.0000x reference)
//
#include <hip/hip_runtime.h>

// RegistrationLoss: sim = -mean(NCC_9x9x9(warped, fixed)), reg = bending energy of flow,
// total = sim + 0.01*reg. Inputs f32: warped[2,1,128,128,128], fixed same, flow[2,3,128,128,128].
// Output: 3 floats [total, sim, reg].
//
// Round-10 structure:
//   wh_bend: ncc_wh phase with NO LDS staging — the W-window comes from 5 unconditional
//            clamped global_load_dwordx2 per source (SGPR base + shared 32-bit voffsets;
//            out-of-row slots killed by 0/1 mask multiplies = exact zero-pad semantics;
//            invalid h rows masked wave-uniformly on the window sums). H-box f32 register
//            ring -> bufB packed bf16 (42 MB). THEN sequential bending phase (grid-strided
//            12 float4-iters/thread). R9 lesson: the LDS round-trip (2 ds_write + 10
//            ds_read/step + 213K bank-conflict cycles) was the serialization.
//   ncc_d:  D-box register ring over 16 d-segments, 1-step register prefetch,
//           uint4+dword loads, NCC + block reduce; f32 accum.
// bufB row layout (per (b,d,h), 320 unsigned = 1280 B):
//   [0,256): uint4{bf2(f0),bf2(f1),bf2(f2),bf2(f3)} per w-pair at 4*wp
//   [256,320): bf2(f4) dword per w-pair
// Lessons kept: no min-waves launch_bounds (R4: VGPR cap -> spill); no per-LANE
// conditional loads (R5: exec-mask serialization); no block-type mixing (R7: residency).

#define DIM 128
#define V   4194304L      // 2*128^3
#define NVOL6 12582912L   // 6*128^3

#define ZER2 make_float2(0.f, 0.f)

__device__ __forceinline__ unsigned pack_bf2(float2 v) {
    unsigned ax = __float_as_uint(v.x), ay = __float_as_uint(v.y);
    ax = ax + 0x7fffu + ((ax >> 16) & 1u);      // round-to-nearest-even
    ay = ay + 0x7fffu + ((ay >> 16) & 1u);
    return (ax >> 16) | (ay & 0xffff0000u);
}
__device__ __forceinline__ float2 unpack_bf2(unsigned u) {
    return make_float2(__uint_as_float(u << 16), __uint_as_float(u & 0xffff0000u));
}

__device__ __forceinline__ float wave_block_reduce_partial(float local, float* lds, int t, int nwaves) {
    #pragma unroll
    for (int off = 32; off > 0; off >>= 1) local += __shfl_down(local, off, 64);
    if ((t & 63) == 0) lds[t >> 6] = local;
    __syncthreads();
    float s = 0.f;
    if (t == 0) {
        for (int i = 0; i < nwaves; ++i) s += lds[i];
    }
    return s; // valid on t==0 only
}

__device__ __forceinline__ float2 ldg2(const float* base, unsigned byteOff) {
    return *reinterpret_cast<const float2*>(reinterpret_cast<const char*>(base) + byteOff);
}

// ---------------- Kernel 1: ncc_wh phase + bending phase ----------------
__global__ __launch_bounds__(256) void wh_bend(const float* __restrict__ I,
                                               const float* __restrict__ J,
                                               const float* __restrict__ F,
                                               unsigned* __restrict__ bufB,
                                               float* __restrict__ regPartial) {
    // ================= phase 1: products + W-box + H-box -> bufB =================
    {
        const int lane = threadIdx.x & 63;
        const int wv   = threadIdx.x >> 6;
        const int wid  = (blockIdx.x << 2) + wv;   // [0, 4096)
        const int e = wid & 15;           // h-chunk
        const int d = (wid >> 4) & 127;
        const int b = wid >> 11;
        const int h0 = e << 3;
        const int w0 = lane << 1;
        const unsigned sliceByte = (unsigned)(b * 128 + d) * 65536u;   // *16384 elems *4 B

        // per-lane clamped w byte-offsets (shared by I and J) and 0/1 masks
        unsigned co4[5];
        float mx[5], my[5];
        #pragma unroll
        for (int o = 0; o < 5; ++o) {
            const int wl = w0 - 4 + 2 * o;
            const int wr = wl + 1;
            const int c = wl < 0 ? 0 : (wl > 126 ? 126 : wl);
            co4[o] = sliceByte + (unsigned)c * 4u;
            mx[o] = ((unsigned)wl < 128u) ? 1.f : 0.f;
            my[o] = ((unsigned)wr < 128u) ? 1.f : 0.f;
        }

        float2 win[9][5];
        float2 hs[5];
        #pragma unroll
        for (int f = 0; f < 5; ++f) hs[f] = ZER2;

        #pragma unroll
        for (int s = 0; s < 16; ++s) {
            const int h_in = h0 - 4 + s;
            const int h_cl = h_in < 0 ? 0 : (h_in > 127 ? 127 : h_in);
            const unsigned rowb = (unsigned)h_cl * 512u;           // wave-uniform
            const float hm = ((unsigned)h_in < 128u) ? 1.f : 0.f;  // wave-uniform

            // 5 shifted views via unconditional clamped loads (L1-served overlap)
            float2 iv[5], jv[5];
            #pragma unroll
            for (int o = 0; o < 5; ++o) {
                const unsigned off = co4[o] + rowb;
                iv[o] = ldg2(I, off);
                jv[o] = ldg2(J, off);
            }
            // mask boundary slots (center o=2 is always valid)
            #pragma unroll
            for (int o = 0; o < 5; ++o) {
                if (o != 2) {
                    iv[o].x *= mx[o]; iv[o].y *= my[o];
                    jv[o].x *= mx[o]; jv[o].y *= my[o];
                }
            }

            float2 v[5][5];
            #pragma unroll
            for (int o = 0; o < 5; ++o) {
                v[0][o] = iv[o];
                v[1][o] = jv[o];
                v[2][o] = make_float2(iv[o].x * iv[o].x, iv[o].y * iv[o].y);
                v[3][o] = make_float2(jv[o].x * jv[o].x, jv[o].y * jv[o].y);
                v[4][o] = make_float2(iv[o].x * jv[o].x, iv[o].y * jv[o].y);
            }

            #pragma unroll
            for (int f = 0; f < 5; ++f) {
                const float core = v[f][1].x + v[f][1].y + v[f][2].x + v[f][2].y
                                 + v[f][3].x + v[f][3].y;
                float2 wb;
                wb.x = (core + v[f][0].x + v[f][0].y + v[f][4].x) * hm;  // window w-4..w+4
                wb.y = (core + v[f][0].y + v[f][4].x + v[f][4].y) * hm;  // window w-3..w+5
                if (s >= 9) { hs[f].x -= win[s % 9][f].x; hs[f].y -= win[s % 9][f].y; }
                hs[f].x += wb.x; hs[f].y += wb.y;
                win[s % 9][f] = wb;
            }

            if (s >= 8) {
                const int h_out = h0 + s - 8;
                unsigned* row = bufB + ((b * 128 + d) * 128 + h_out) * 320;
                const uint4 pk = make_uint4(pack_bf2(hs[0]), pack_bf2(hs[1]),
                                            pack_bf2(hs[2]), pack_bf2(hs[3]));
                *reinterpret_cast<uint4*>(row + 4 * lane) = pk;
                row[256 + lane] = pack_bf2(hs[4]);
            }
        }
    }

    // ================= phase 2: bending energy (tail-fill, grid-strided) =================
    {
        const float invS = 1.0f / 12386304.0f;   // 6*126*128*128  (i==j)
        const float invC = 1.0f / 12289536.0f;   // 6*127*126*128  (i!=j, both orderings)
        float local = 0.f;

        #pragma unroll 2
        for (int it = 0; it < 12; ++it) {
            const int tid = (blockIdx.x + it * 1024) * 256 + threadIdx.x;  // [0, 3145728)
            const long e = (long)tid << 2;                                  // element base
            const int r = (int)(e & 2097151);
            const int d = r >> 14;
            const int h = (r >> 7) & 127;
            const int w0 = r & 127;                                         // 0,4,...,124

            const float* p = F + e;
            const int off4 = (w0 < 124) ? 4 : 0;
            const int oD  = (d < 127) ? 16384 : 0;
            const int oD2 = (d < 126) ? 32768 : 0;
            const int oH  = (h < 127) ? 128 : 0;
            const int oH2 = (h < 126) ? 256 : 0;

            const float4 a0  = *reinterpret_cast<const float4*>(p);
            const float2 s45 = *reinterpret_cast<const float2*>(p + off4);
            const float4 aD  = *reinterpret_cast<const float4*>(p + oD);
            const float  sD4 = (p + oD)[off4];
            const float4 aD2 = *reinterpret_cast<const float4*>(p + oD2);
            const float4 aH  = *reinterpret_cast<const float4*>(p + oH);
            const float  sH4 = (p + oH)[off4];
            const float4 aH2 = *reinterpret_cast<const float4*>(p + oH2);
            const float4 aDH = *reinterpret_cast<const float4*>(p + oD + oH);

            const float A0[6] = {a0.x, a0.y, a0.z, a0.w, s45.x, s45.y};
            const float AD[5] = {aD.x, aD.y, aD.z, aD.w, sD4};
            const float AH[5] = {aH.x, aH.y, aH.z, aH.w, sH4};
            const float AD2[4] = {aD2.x, aD2.y, aD2.z, aD2.w};
            const float AH2[4] = {aH2.x, aH2.y, aH2.z, aH2.w};
            const float ADH[4] = {aDH.x, aDH.y, aDH.z, aDH.w};

            const float mD2 = (d < 126) ? invS : 0.f;
            const float mH2 = (h < 126) ? invS : 0.f;
            const float cD  = (d < 126) ? 1.f : 0.f;
            const float cH  = (h < 126) ? 1.f : 0.f;
            const bool  vD  = d < 127, vH = h < 127;

            #pragma unroll
            for (int k = 0; k < 4; ++k) {
                const int wk = w0 + k;
                const float mW2 = (wk < 126) ? invS : 0.f;
                const float cW  = (wk < 126) ? 1.f : 0.f;
                const bool  vW  = wk < 127;

                const float xW = A0[k + 2] - 2.f * A0[k + 1] + A0[k];
                local += xW * xW * mW2;
                const float xD = AD2[k] - 2.f * AD[k] + A0[k];
                local += xD * xD * mD2;
                const float xH = AH2[k] - 2.f * AH[k] + A0[k];
                local += xH * xH * mH2;

                const float xDH = ADH[k] - AD[k] - AH[k] + A0[k];
                local += xDH * xDH * (((vD && vH) ? (cD + cH) : 0.f) * invC);
                const float xDW = AD[k + 1] - AD[k] - A0[k + 1] + A0[k];
                local += xDW * xDW * (((vD && vW) ? (cD + cW) : 0.f) * invC);
                const float xHW = AH[k + 1] - AH[k] - A0[k + 1] + A0[k];
                local += xHW * xHW * (((vH && vW) ? (cH + cW) : 0.f) * invC);
            }
        }

        __shared__ float rl[4];
        const float s = wave_block_reduce_partial(local, rl, threadIdx.x, 4);
        if (threadIdx.x == 0) regPartial[blockIdx.x] = s;
    }
}

// ---------------- Kernel 2: D-box + NCC + block reduce ----------------
// Block = (b, h, seg-group). 256 threads = w-pair(64) x 4 segs (sg wave-uniform).
// Each seg: 8 owned d + 8 halo. 1-step register prefetch of the 20 B row slice.
__global__ __launch_bounds__(256) void ncc_d(const unsigned* __restrict__ bufB,
                                             float* __restrict__ nccPartial) {
    const int t = threadIdx.x;
    const int wp = t & 63;             // w-pair index
    const int sg = t >> 6;             // 0..3 (wave-uniform)
    const int b = blockIdx.x >> 9;
    const int h = (blockIdx.x >> 2) & 127;
    const int g = blockIdx.x & 3;
    const int d0 = ((g << 2) + sg) << 3;   // owned d: d0..d0+7
    const float inv_n = 1.0f / 729.0f;

    unsigned win[9][5];
    float2 rs[5];
    #pragma unroll
    for (int f = 0; f < 5; ++f) rs[f] = ZER2;
    float local = 0.f;

    // prefetch step 0 (dd = d0-4)
    uint4 nx = make_uint4(0u, 0u, 0u, 0u);
    unsigned nx4 = 0u;
    {
        const int dd = d0 - 4;
        if ((unsigned)dd < 128u) {
            const unsigned* row = bufB + ((b * 128 + dd) * 128 + h) * 320;
            nx = *reinterpret_cast<const uint4*>(row + 4 * wp);
            nx4 = row[256 + wp];
        }
    }

    #pragma unroll
    for (int s = 0; s < 16; ++s) {
        const uint4 cx = nx;
        const unsigned cx4 = nx4;
        if (s < 15) {
            const int dd = d0 - 3 + s;
            if ((unsigned)dd < 128u) {
                const unsigned* row = bufB + ((b * 128 + dd) * 128 + h) * 320;
                nx = *reinterpret_cast<const uint4*>(row + 4 * wp);
                nx4 = row[256 + wp];
            } else {
                nx = make_uint4(0u, 0u, 0u, 0u); nx4 = 0u;
            }
        }

        const unsigned x[5] = {cx.x, cx.y, cx.z, cx.w, cx4};
        #pragma unroll
        for (int f = 0; f < 5; ++f) {
            if (s >= 9) {
                const float2 o = unpack_bf2(win[s % 9][f]);
                rs[f].x -= o.x; rs[f].y -= o.y;
            }
            const float2 nv = unpack_bf2(x[f]);
            rs[f].x += nv.x; rs[f].y += nv.y;
            win[s % 9][f] = x[f];
        }
        if (s >= 8) {
            const float uix = rs[0].x * inv_n, uiy = rs[0].y * inv_n;
            const float ujx = rs[1].x * inv_n, ujy = rs[1].y * inv_n;
            const float i2x = rs[2].x * inv_n - uix * uix;
            const float i2y = rs[2].y * inv_n - uiy * uiy;
            const float j2x = rs[3].x * inv_n - ujx * ujx;
            const float j2y = rs[3].y * inv_n - ujy * ujy;
            const float ijx = rs[4].x * inv_n - uix * ujx;
            const float ijy = rs[4].y * inv_n - uiy * ujy;
            local += ijx * ijx / (i2x * j2x + 1e-5f)
                   + ijy * ijy / (i2y * j2y + 1e-5f);
        }
    }

    __shared__ float lds[4];
    const float s = wave_block_reduce_partial(local, lds, t, 4);
    if (t == 0) nccPartial[blockIdx.x] = s;
}

// ---------------- Finalize ----------------
__global__ void finalize(const float* __restrict__ nccPartial, const float* __restrict__ regPartial,
                         float* __restrict__ out) {
    __shared__ float sdata[256];
    const int t = threadIdx.x;
    float a = 0.f;
    for (int i = t; i < 1024; i += 256) a += nccPartial[i];
    sdata[t] = a; __syncthreads();
    for (int s = 128; s > 0; s >>= 1) { if (t < s) sdata[t] += sdata[t + s]; __syncthreads(); }
    const float nccSum = sdata[0];
    __syncthreads();
    float bsum = 0.f;
    for (int i = t; i < 1024; i += 256) bsum += regPartial[i];
    sdata[t] = bsum; __syncthreads();
    for (int s = 128; s > 0; s >>= 1) { if (t < s) sdata[t] += sdata[t + s]; __syncthreads(); }
    if (t == 0) {
        const float reg = sdata[0];
        const float sim = -nccSum / (float)V;
        out[0] = sim + 0.01f * reg;
        out[1] = sim;
        out[2] = reg;
    }
}

extern "C" void kernel_launch(void* const* d_in, const int* in_sizes, int n_in,
                              void* d_out, int out_size, void* d_ws, size_t ws_size,
                              hipStream_t stream) {
    const float* warped = (const float*)d_in[0];
    const float* fixedv = (const float*)d_in[1];
    const float* flow   = (const float*)d_in[2];
    float* out = (float*)d_out;
    float* ws  = (float*)d_ws;

    // ws layout (floats): [0,1024) nccPartial | [1024,2048) regPartial | pad |
    //                     [16384, ...) bufB packed bf16 (2*128^3*5*2B ~= 42 MB)
    float* nccPartial = ws;
    float* regPartial = ws + 1024;
    unsigned* bufB = (unsigned*)(ws + 16384);

    // 1024 blocks = 4096 wh-waves (wave = (b, d, h-chunk of 8)) + bending tail-fill
    wh_bend<<<dim3(1024), dim3(256), 0, stream>>>(warped, fixedv, flow, bufB, regPartial);
    // 1024 blocks = (b, h, seg-group); 256 threads = w-pair x 4 d-segments
    ncc_d<<<dim3(1024), dim3(256), 0, stream>>>(bufB, nccPartial);
    finalize<<<dim3(1), dim3(256), 0, stream>>>(nccPartial, regPartial, out);
}

// Round 11
// 54.592 us; speedup vs baseline: 1.2941x; 1.2941x over previous
//
#include <hip/hip_runtime.h>

// RegistrationLoss: sim = -mean(NCC_9x9x9(warped, fixed)), reg = bending energy of flow,
// total = sim + 0.01*reg. Inputs f32: warped[2,1,128,128,128], fixed same, flow[2,3,128,128,128].
// Output: 3 floats [total, sim, reg].
//
// Round-11 structure (R9 + DPP W-window):
//   wh_bend: ncc_wh phase — per h-step: 1-deep prefetched center float2 loads of I,J,
//            then the 5 shifted W-views via v_mov_dpp wave_shr:1/wave_shl:1 chains
//            (pure VALU, bound_ctrl zero-fill == zero-pad boundary), products, W-box,
//            H-box f32 register ring -> bufB packed bf16 (42 MB). THEN sequential
//            bending phase (grid-strided 12 float4-iters/thread).
//            R9 lesson: LDS round-trip (2 ds_write + 10 ds_read/step, 213K conflict
//            cycles, lgkm write->read chain) was the serializer. R10 lesson: replacing
//            it with 10 clamped VMEM loads/step costs 152 VGPR + VMEM issue — worse.
//            DPP costs 16 VALU movs/step and zero memory.
//   ncc_d:  D-box register ring over 16 d-segments, 1-step register prefetch,
//           uint4+dword loads, NCC + block reduce; f32 accum. (unchanged from R9)
// bufB row layout (per (b,d,h), 320 unsigned = 1280 B):
//   [0,256): uint4{bf2(f0),bf2(f1),bf2(f2),bf2(f3)} per w-pair at 4*wp
//   [256,320): bf2(f4) dword per w-pair
// Lessons kept: no min-waves launch_bounds (R4: VGPR cap -> spill); no per-LANE
// conditional loads (R5: exec-mask serialization); no block-type mixing (R7: residency).

#define DIM 128
#define V   4194304L      // 2*128^3
#define NVOL6 12582912L   // 6*128^3

#define ZER2 make_float2(0.f, 0.f)

__device__ __forceinline__ unsigned pack_bf2(float2 v) {
    unsigned ax = __float_as_uint(v.x), ay = __float_as_uint(v.y);
    ax = ax + 0x7fffu + ((ax >> 16) & 1u);      // round-to-nearest-even
    ay = ay + 0x7fffu + ((ay >> 16) & 1u);
    return (ax >> 16) | (ay & 0xffff0000u);
}
__device__ __forceinline__ float2 unpack_bf2(unsigned u) {
    return make_float2(__uint_as_float(u << 16), __uint_as_float(u & 0xffff0000u));
}

// DPP wave-wide lane shifts. wave_shr:1 (0x138): lane i <- lane i-1 (lane 0 -> 0).
// wave_shl:1 (0x130): lane i <- lane i+1 (lane 63 -> 0). bound_ctrl=true: zero-fill.
__device__ __forceinline__ float dpp_up1(float x) {   // from lower lane
    return __int_as_float(__builtin_amdgcn_mov_dpp(__float_as_int(x), 0x138, 0xF, 0xF, true));
}
__device__ __forceinline__ float dpp_dn1(float x) {   // from higher lane
    return __int_as_float(__builtin_amdgcn_mov_dpp(__float_as_int(x), 0x130, 0xF, 0xF, true));
}
__device__ __forceinline__ float2 dpp_up1_f2(float2 v) {
    return make_float2(dpp_up1(v.x), dpp_up1(v.y));
}
__device__ __forceinline__ float2 dpp_dn1_f2(float2 v) {
    return make_float2(dpp_dn1(v.x), dpp_dn1(v.y));
}

__device__ __forceinline__ float wave_block_reduce_partial(float local, float* lds, int t, int nwaves) {
    #pragma unroll
    for (int off = 32; off > 0; off >>= 1) local += __shfl_down(local, off, 64);
    if ((t & 63) == 0) lds[t >> 6] = local;
    __syncthreads();
    float s = 0.f;
    if (t == 0) {
        for (int i = 0; i < nwaves; ++i) s += lds[i];
    }
    return s; // valid on t==0 only
}

// ---------------- Kernel 1: ncc_wh phase + bending phase ----------------
__global__ __launch_bounds__(256) void wh_bend(const float* __restrict__ I,
                                               const float* __restrict__ J,
                                               const float* __restrict__ F,
                                               unsigned* __restrict__ bufB,
                                               float* __restrict__ regPartial) {
    // ================= phase 1: products + W-box + H-box -> bufB =================
    {
        const int lane = threadIdx.x & 63;
        const int wv   = threadIdx.x >> 6;
        const int wid  = (blockIdx.x << 2) + wv;   // [0, 4096)
        const int e = wid & 15;           // h-chunk
        const int d = (wid >> 4) & 127;
        const int b = wid >> 11;
        const int h0 = e << 3;
        const int w0 = lane << 1;
        const float* baseI = I + (b * 128 + d) * 16384 + w0;
        const float* baseJ = J + (b * 128 + d) * 16384 + w0;

        float2 win[9][5];
        float2 hs[5];
        #pragma unroll
        for (int f = 0; f < 5; ++f) hs[f] = ZER2;

        // 1-step prefetch of the center float2 (wave-uniform row guard)
        float2 na = ZER2, nb = ZER2;
        {
            const int h = h0 - 4;
            if ((unsigned)h < 128u) {
                na = *reinterpret_cast<const float2*>(baseI + h * 128);
                nb = *reinterpret_cast<const float2*>(baseJ + h * 128);
            }
        }

        #pragma unroll
        for (int s = 0; s < 16; ++s) {
            const float2 ci = na, cj = nb;
            if (s < 15) {
                const int h = h0 - 3 + s;
                if ((unsigned)h < 128u) {
                    na = *reinterpret_cast<const float2*>(baseI + h * 128);
                    nb = *reinterpret_cast<const float2*>(baseJ + h * 128);
                } else {
                    na = ZER2; nb = ZER2;
                }
            }

            // 5 shifted W-views via DPP lane shifts (element offsets -4,-2,0,+2,+4)
            float2 iv[5], jv[5];
            iv[2] = ci;              jv[2] = cj;
            iv[1] = dpp_up1_f2(ci);  jv[1] = dpp_up1_f2(cj);
            iv[0] = dpp_up1_f2(iv[1]); jv[0] = dpp_up1_f2(jv[1]);
            iv[3] = dpp_dn1_f2(ci);  jv[3] = dpp_dn1_f2(cj);
            iv[4] = dpp_dn1_f2(iv[3]); jv[4] = dpp_dn1_f2(jv[3]);

            float2 v[5][5];
            #pragma unroll
            for (int o = 0; o < 5; ++o) {
                v[0][o] = iv[o];
                v[1][o] = jv[o];
                v[2][o] = make_float2(iv[o].x * iv[o].x, iv[o].y * iv[o].y);
                v[3][o] = make_float2(jv[o].x * jv[o].x, jv[o].y * jv[o].y);
                v[4][o] = make_float2(iv[o].x * jv[o].x, iv[o].y * jv[o].y);
            }

            #pragma unroll
            for (int f = 0; f < 5; ++f) {
                const float core = v[f][1].x + v[f][1].y + v[f][2].x + v[f][2].y
                                 + v[f][3].x + v[f][3].y;
                float2 wb;
                wb.x = core + v[f][0].x + v[f][0].y + v[f][4].x;   // window w-4..w+4
                wb.y = core + v[f][0].y + v[f][4].x + v[f][4].y;   // window w-3..w+5
                if (s >= 9) { hs[f].x -= win[s % 9][f].x; hs[f].y -= win[s % 9][f].y; }
                hs[f].x += wb.x; hs[f].y += wb.y;
                win[s % 9][f] = wb;
            }

            if (s >= 8) {
                const int h_out = h0 + s - 8;
                unsigned* row = bufB + ((b * 128 + d) * 128 + h_out) * 320;
                const uint4 pk = make_uint4(pack_bf2(hs[0]), pack_bf2(hs[1]),
                                            pack_bf2(hs[2]), pack_bf2(hs[3]));
                *reinterpret_cast<uint4*>(row + 4 * lane) = pk;
                row[256 + lane] = pack_bf2(hs[4]);
            }
        }
    }

    // ================= phase 2: bending energy (tail-fill, grid-strided) =================
    {
        const float invS = 1.0f / 12386304.0f;   // 6*126*128*128  (i==j)
        const float invC = 1.0f / 12289536.0f;   // 6*127*126*128  (i!=j, both orderings)
        float local = 0.f;

        #pragma unroll 2
        for (int it = 0; it < 12; ++it) {
            const int tid = (blockIdx.x + it * 1024) * 256 + threadIdx.x;  // [0, 3145728)
            const long e = (long)tid << 2;                                  // element base
            const int r = (int)(e & 2097151);
            const int d = r >> 14;
            const int h = (r >> 7) & 127;
            const int w0 = r & 127;                                         // 0,4,...,124

            const float* p = F + e;
            const int off4 = (w0 < 124) ? 4 : 0;
            const int oD  = (d < 127) ? 16384 : 0;
            const int oD2 = (d < 126) ? 32768 : 0;
            const int oH  = (h < 127) ? 128 : 0;
            const int oH2 = (h < 126) ? 256 : 0;

            const float4 a0  = *reinterpret_cast<const float4*>(p);
            const float2 s45 = *reinterpret_cast<const float2*>(p + off4);
            const float4 aD  = *reinterpret_cast<const float4*>(p + oD);
            const float  sD4 = (p + oD)[off4];
            const float4 aD2 = *reinterpret_cast<const float4*>(p + oD2);
            const float4 aH  = *reinterpret_cast<const float4*>(p + oH);
            const float  sH4 = (p + oH)[off4];
            const float4 aH2 = *reinterpret_cast<const float4*>(p + oH2);
            const float4 aDH = *reinterpret_cast<const float4*>(p + oD + oH);

            const float A0[6] = {a0.x, a0.y, a0.z, a0.w, s45.x, s45.y};
            const float AD[5] = {aD.x, aD.y, aD.z, aD.w, sD4};
            const float AH[5] = {aH.x, aH.y, aH.z, aH.w, sH4};
            const float AD2[4] = {aD2.x, aD2.y, aD2.z, aD2.w};
            const float AH2[4] = {aH2.x, aH2.y, aH2.z, aH2.w};
            const float ADH[4] = {aDH.x, aDH.y, aDH.z, aDH.w};

            const float mD2 = (d < 126) ? invS : 0.f;
            const float mH2 = (h < 126) ? invS : 0.f;
            const float cD  = (d < 126) ? 1.f : 0.f;
            const float cH  = (h < 126) ? 1.f : 0.f;
            const bool  vD  = d < 127, vH = h < 127;

            #pragma unroll
            for (int k = 0; k < 4; ++k) {
                const int wk = w0 + k;
                const float mW2 = (wk < 126) ? invS : 0.f;
                const float cW  = (wk < 126) ? 1.f : 0.f;
                const bool  vW  = wk < 127;

                const float xW = A0[k + 2] - 2.f * A0[k + 1] + A0[k];
                local += xW * xW * mW2;
                const float xD = AD2[k] - 2.f * AD[k] + A0[k];
                local += xD * xD * mD2;
                const float xH = AH2[k] - 2.f * AH[k] + A0[k];
                local += xH * xH * mH2;

                const float xDH = ADH[k] - AD[k] - AH[k] + A0[k];
                local += xDH * xDH * (((vD && vH) ? (cD + cH) : 0.f) * invC);
                const float xDW = AD[k + 1] - AD[k] - A0[k + 1] + A0[k];
                local += xDW * xDW * (((vD && vW) ? (cD + cW) : 0.f) * invC);
                const float xHW = AH[k + 1] - AH[k] - A0[k + 1] + A0[k];
                local += xHW * xHW * (((vH && vW) ? (cH + cW) : 0.f) * invC);
            }
        }

        __shared__ float rl[4];
        const float s = wave_block_reduce_partial(local, rl, threadIdx.x, 4);
        if (threadIdx.x == 0) regPartial[blockIdx.x] = s;
    }
}

// ---------------- Kernel 2: D-box + NCC + block reduce ----------------
// Block = (b, h, seg-group). 256 threads = w-pair(64) x 4 segs (sg wave-uniform).
// Each seg: 8 owned d + 8 halo. 1-step register prefetch of the 20 B row slice.
__global__ __launch_bounds__(256) void ncc_d(const unsigned* __restrict__ bufB,
                                             float* __restrict__ nccPartial) {
    const int t = threadIdx.x;
    const int wp = t & 63;             // w-pair index
    const int sg = t >> 6;             // 0..3 (wave-uniform)
    const int b = blockIdx.x >> 9;
    const int h = (blockIdx.x >> 2) & 127;
    const int g = blockIdx.x & 3;
    const int d0 = ((g << 2) + sg) << 3;   // owned d: d0..d0+7
    const float inv_n = 1.0f / 729.0f;

    unsigned win[9][5];
    float2 rs[5];
    #pragma unroll
    for (int f = 0; f < 5; ++f) rs[f] = ZER2;
    float local = 0.f;

    // prefetch step 0 (dd = d0-4)
    uint4 nx = make_uint4(0u, 0u, 0u, 0u);
    unsigned nx4 = 0u;
    {
        const int dd = d0 - 4;
        if ((unsigned)dd < 128u) {
            const unsigned* row = bufB + ((b * 128 + dd) * 128 + h) * 320;
            nx = *reinterpret_cast<const uint4*>(row + 4 * wp);
            nx4 = row[256 + wp];
        }
    }

    #pragma unroll
    for (int s = 0; s < 16; ++s) {
        const uint4 cx = nx;
        const unsigned cx4 = nx4;
        if (s < 15) {
            const int dd = d0 - 3 + s;
            if ((unsigned)dd < 128u) {
                const unsigned* row = bufB + ((b * 128 + dd) * 128 + h) * 320;
                nx = *reinterpret_cast<const uint4*>(row + 4 * wp);
                nx4 = row[256 + wp];
            } else {
                nx = make_uint4(0u, 0u, 0u, 0u); nx4 = 0u;
            }
        }

        const unsigned x[5] = {cx.x, cx.y, cx.z, cx.w, cx4};
        #pragma unroll
        for (int f = 0; f < 5; ++f) {
            if (s >= 9) {
                const float2 o = unpack_bf2(win[s % 9][f]);
                rs[f].x -= o.x; rs[f].y -= o.y;
            }
            const float2 nv = unpack_bf2(x[f]);
            rs[f].x += nv.x; rs[f].y += nv.y;
            win[s % 9][f] = x[f];
        }
        if (s >= 8) {
            const float uix = rs[0].x * inv_n, uiy = rs[0].y * inv_n;
            const float ujx = rs[1].x * inv_n, ujy = rs[1].y * inv_n;
            const float i2x = rs[2].x * inv_n - uix * uix;
            const float i2y = rs[2].y * inv_n - uiy * uiy;
            const float j2x = rs[3].x * inv_n - ujx * ujx;
            const float j2y = rs[3].y * inv_n - ujy * ujy;
            const float ijx = rs[4].x * inv_n - uix * ujx;
            const float ijy = rs[4].y * inv_n - uiy * ujy;
            local += ijx * ijx / (i2x * j2x + 1e-5f)
                   + ijy * ijy / (i2y * j2y + 1e-5f);
        }
    }

    __shared__ float lds[4];
    const float s = wave_block_reduce_partial(local, lds, t, 4);
    if (t == 0) nccPartial[blockIdx.x] = s;
}

// ---------------- Finalize ----------------
__global__ void finalize(const float* __restrict__ nccPartial, const float* __restrict__ regPartial,
                         float* __restrict__ out) {
    __shared__ float sdata[256];
    const int t = threadIdx.x;
    float a = 0.f;
    for (int i = t; i < 1024; i += 256) a += nccPartial[i];
    sdata[t] = a; __syncthreads();
    for (int s = 128; s > 0; s >>= 1) { if (t < s) sdata[t] += sdata[t + s]; __syncthreads(); }
    const float nccSum = sdata[0];
    __syncthreads();
    float bsum = 0.f;
    for (int i = t; i < 1024; i += 256) bsum += regPartial[i];
    sdata[t] = bsum; __syncthreads();
    for (int s = 128; s > 0; s >>= 1) { if (t < s) sdata[t] += sdata[t + s]; __syncthreads(); }
    if (t == 0) {
        const float reg = sdata[0];
        const float sim = -nccSum / (float)V;
        out[0] = sim + 0.01f * reg;
        out[1] = sim;
        out[2] = reg;
    }
}

extern "C" void kernel_launch(void* const* d_in, const int* in_sizes, int n_in,
                              void* d_out, int out_size, void* d_ws, size_t ws_size,
                              hipStream_t stream) {
    const float* warped = (const float*)d_in[0];
    const float* fixedv = (const float*)d_in[1];
    const float* flow   = (const float*)d_in[2];
    float* out = (float*)d_out;
    float* ws  = (float*)d_ws;

    // ws layout (floats): [0,1024) nccPartial | [1024,2048) regPartial | pad |
    //                     [16384, ...) bufB packed bf16 (2*128^3*5*2B ~= 42 MB)
    float* nccPartial = ws;
    float* regPartial = ws + 1024;
    unsigned* bufB = (unsigned*)(ws + 16384);

    // 1024 blocks = 4096 wh-waves (wave = (b, d, h-chunk of 8)) + bending tail-fill
    wh_bend<<<dim3(1024), dim3(256), 0, stream>>>(warped, fixedv, flow, bufB, regPartial);
    // 1024 blocks = (b, h, seg-group); 256 threads = w-pair x 4 d-segments
    ncc_d<<<dim3(1024), dim3(256), 0, stream>>>(bufB, nccPartial);
    finalize<<<dim3(1), dim3(256), 0, stream>>>(nccPartial, regPartial, out);
}